// Round 1
// baseline (722.073 us; speedup 1.0000x reference)
//
#include <hip/hip_runtime.h>

#define HID 128
#define OUTC 64
#define INC 3

// ---------------- degree / dinv ----------------

__global__ void count_deg_kernel(const int* __restrict__ dst, int E, int* __restrict__ degi) {
    int i = blockIdx.x * blockDim.x + threadIdx.x;
    if (i < E) atomicAdd(&degi[dst[i]], 1);
}

// in place: int count -> float rsqrt(count + 1)   (+1 = self loop)
__global__ void dinv_kernel(int* __restrict__ degi, int N) {
    int i = blockIdx.x * blockDim.x + threadIdx.x;
    if (i < N) {
        int d = degi[i] + 1;
        float* f = (float*)degi;
        f[i] = rsqrtf((float)d);
    }
}

// ---------------- layer 1 matmul: hs1 = dinv * (x @ W1), [N,3]@[3,128] ----------------

__global__ void mm1_kernel(const float* __restrict__ x, const float* __restrict__ W1,
                           const float* __restrict__ dinv, float* __restrict__ hs1, int N) {
    __shared__ float w[INC * HID];
    for (int t = threadIdx.x; t < INC * HID; t += blockDim.x) w[t] = W1[t];
    __syncthreads();
    int idx = blockIdx.x * blockDim.x + threadIdx.x;
    int i = idx >> 7, j = idx & 127;
    if (i < N) {
        float x0 = x[i * 3 + 0], x1 = x[i * 3 + 1], x2 = x[i * 3 + 2];
        float v = x0 * w[j] + x1 * w[HID + j] + x2 * w[2 * HID + j];
        hs1[idx] = dinv[i] * v;
    }
}

// ---------------- edge scatter: agg[dst] += h[src], one thread per (edge,feature) ----------------

template <int LOGF>
__global__ void scatter_kernel(const int* __restrict__ src, const int* __restrict__ dst,
                               long long E, const float* __restrict__ h,
                               float* __restrict__ agg) {
    long long idx = (long long)blockIdx.x * blockDim.x + threadIdx.x;
    if (idx < (E << LOGF)) {
        int e = (int)(idx >> LOGF);
        int j = (int)(idx & ((1 << LOGF) - 1));
        int s = src[e], d = dst[e];
        atomicAdd(&agg[((long long)d << LOGF) + j], h[((long long)s << LOGF) + j]);
    }
}

// ---------------- layer-1 epilogue: a1 = relu(dinv*(hs1 + agg1) + b1), in place over hs1 ----------------

__global__ void relu_bias_kernel(const float* __restrict__ agg, const float* __restrict__ dinv,
                                 const float* __restrict__ b, float* __restrict__ hs, int N) {
    int idx = blockIdx.x * blockDim.x + threadIdx.x;
    if (idx < N * HID) {
        int i = idx >> 7, j = idx & 127;
        float v = dinv[i] * (hs[idx] + agg[idx]) + b[j];
        hs[idx] = fmaxf(v, 0.0f);
    }
}

// ---------------- layer 2 matmul: hs2 = dinv * (a1 @ W2), [N,128]@[128,64] ----------------
// one 64-thread block per node; row staged in LDS; W2 (32 KB) served from L1/L2

__global__ void mm2_kernel(const float* __restrict__ a1, const float* __restrict__ W2,
                           const float* __restrict__ dinv, float* __restrict__ hs2, int N) {
    __shared__ float row[HID];
    int i = blockIdx.x;
    int j = threadIdx.x;  // 0..63
    row[j] = a1[(long long)i * HID + j];
    row[j + 64] = a1[(long long)i * HID + 64 + j];
    __syncthreads();
    float acc = 0.0f;
#pragma unroll
    for (int k = 0; k < HID; ++k) acc += row[k] * W2[k * OUTC + j];
    hs2[(long long)i * OUTC + j] = dinv[i] * acc;
}

// ---------------- layer-2 epilogue: out = dinv*(hs2 + agg2) + b2 ----------------

__global__ void final_kernel(const float* __restrict__ agg2, const float* __restrict__ hs2,
                             const float* __restrict__ dinv, const float* __restrict__ b2,
                             float* __restrict__ out, int N) {
    int idx = blockIdx.x * blockDim.x + threadIdx.x;
    if (idx < N * OUTC) {
        int i = idx >> 6, j = idx & 63;
        out[idx] = dinv[i] * (hs2[idx] + agg2[idx]) + b2[j];
    }
}

extern "C" void kernel_launch(void* const* d_in, const int* in_sizes, int n_in,
                              void* d_out, int out_size, void* d_ws, size_t ws_size,
                              hipStream_t stream) {
    const float* x  = (const float*)d_in[0];
    const int*   ei = (const int*)d_in[1];
    const float* W1 = (const float*)d_in[2];
    const float* b1 = (const float*)d_in[3];
    const float* W2 = (const float*)d_in[4];
    const float* b2 = (const float*)d_in[5];
    float* out = (float*)d_out;

    const int N = in_sizes[0] / INC;
    const long long E = in_sizes[1] / 2;
    const int* src = ei;
    const int* dst = ei + E;

    // workspace layout: [dinv: 256KB pad][bufA: N*128 f32][bufB: N*128 f32]
    char* ws = (char*)d_ws;
    int*   degi = (int*)ws;
    float* dinv = (float*)ws;
    float* bufA = (float*)(ws + 256 * 1024);
    float* bufB = (float*)(ws + 256 * 1024 + (size_t)N * HID * sizeof(float));

    const int B = 256;

    // degree + dinv (shared by both layers)
    hipMemsetAsync(degi, 0, (size_t)N * sizeof(int), stream);
    count_deg_kernel<<<(int)((E + B - 1) / B), B, 0, stream>>>(dst, (int)E, degi);
    dinv_kernel<<<(N + B - 1) / B, B, 0, stream>>>(degi, N);

    // ---- layer 1 ----
    hipMemsetAsync(bufB, 0, (size_t)N * HID * sizeof(float), stream);          // agg1 = 0
    mm1_kernel<<<((long long)N * HID + B - 1) / B, B, 0, stream>>>(x, W1, dinv, bufA, N);
    {
        long long tot = E << 7;
        scatter_kernel<7><<<(int)((tot + B - 1) / B), B, 0, stream>>>(src, dst, E, bufA, bufB);
    }
    relu_bias_kernel<<<((long long)N * HID + B - 1) / B, B, 0, stream>>>(bufB, dinv, b1, bufA, N);

    // ---- layer 2 ----
    mm2_kernel<<<N, 64, 0, stream>>>(bufA, W2, dinv, bufB, N);                 // hs2 -> bufB
    hipMemsetAsync(bufA, 0, (size_t)N * OUTC * sizeof(float), stream);         // agg2 = 0 (a1 dead)
    {
        long long tot = E << 6;
        scatter_kernel<6><<<(int)((tot + B - 1) / B), B, 0, stream>>>(src, dst, E, bufB, bufA);
    }
    final_kernel<<<((long long)N * OUTC + B - 1) / B, B, 0, stream>>>(bufA, bufB, dinv, b2, out, N);
}

// Round 2
// 416.304 us; speedup vs baseline: 1.7345x; 1.7345x over previous
//
#include <hip/hip_runtime.h>

#define HID 128
#define OUTC 64
#define INC 3
#define BCAP 64        // bucket capacity per node; in-deg ~ Poisson(16), P(>=64) ~ 2e-18
#define OVF_CAP 8192   // overflow edge list capacity (expected usage: 0)

// ---------------- degree / dinv ----------------

__global__ void count_deg_kernel(const int* __restrict__ dst, int E, int* __restrict__ degi) {
    int i = blockIdx.x * blockDim.x + threadIdx.x;
    if (i < E) atomicAdd(&degi[dst[i]], 1);
}

// in place: int count -> float rsqrt(count + 1)   (+1 = self loop)
__global__ void dinv_kernel(int* __restrict__ degi, int N) {
    int i = blockIdx.x * blockDim.x + threadIdx.x;
    if (i < N) {
        int d = degi[i] + 1;
        ((float*)degi)[i] = rsqrtf((float)d);
    }
}

// ---------------- layer 1 in 3-dim space: z = dinv*x ; aggz[dst] += z[src] ----------------
// (aggregation is linear: (sum dinv_s x_s) @ W1 == sum dinv_s (x_s @ W1))

__global__ void z_kernel(const float* __restrict__ x, const float* __restrict__ dinv,
                         float* __restrict__ z, int N) {
    int i = blockIdx.x * blockDim.x + threadIdx.x;
    if (i < N) {
        float di = dinv[i];
        z[3 * i]     = di * x[3 * i];
        z[3 * i + 1] = di * x[3 * i + 1];
        z[3 * i + 2] = di * x[3 * i + 2];
    }
}

__global__ void scatter_z_kernel(const int* __restrict__ src, const int* __restrict__ dst, int E,
                                 const float* __restrict__ z, float* __restrict__ aggz) {
    int e = blockIdx.x * blockDim.x + threadIdx.x;
    if (e < E) {
        int s = src[e], d = dst[e];
        atomicAdd(&aggz[3 * d],     z[3 * s]);
        atomicAdd(&aggz[3 * d + 1], z[3 * s + 1]);
        atomicAdd(&aggz[3 * d + 2], z[3 * s + 2]);
    }
}

// a1 = relu( (dinv*(z+aggz)) @ W1 + b1 )
__global__ void a1_kernel(const float* __restrict__ z, const float* __restrict__ aggz,
                          const float* __restrict__ dinv, const float* __restrict__ W1,
                          const float* __restrict__ b1, float* __restrict__ a1, int N) {
    __shared__ float w[INC * HID];
    for (int t = threadIdx.x; t < INC * HID; t += blockDim.x) w[t] = W1[t];
    __syncthreads();
    int idx = blockIdx.x * blockDim.x + threadIdx.x;
    int i = idx >> 7, j = idx & 127;
    if (i < N) {
        float di = dinv[i];
        float u0 = di * (z[3 * i]     + aggz[3 * i]);
        float u1 = di * (z[3 * i + 1] + aggz[3 * i + 1]);
        float u2 = di * (z[3 * i + 2] + aggz[3 * i + 2]);
        float v = u0 * w[j] + u1 * w[HID + j] + u2 * w[2 * HID + j] + b1[j];
        a1[idx] = fmaxf(v, 0.0f);
    }
}

// ---------------- layer 2 matmul: hs2 = dinv * (a1 @ W2), [N,128]@[128,64] ----------------

__global__ void mm2_kernel(const float* __restrict__ a1, const float* __restrict__ W2,
                           const float* __restrict__ dinv, float* __restrict__ hs2, int N) {
    __shared__ float row[HID];
    int i = blockIdx.x;
    int j = threadIdx.x;  // 0..63
    row[j] = a1[(long long)i * HID + j];
    row[j + 64] = a1[(long long)i * HID + 64 + j];
    __syncthreads();
    float acc = 0.0f;
#pragma unroll
    for (int k = 0; k < HID; ++k) acc += row[k] * W2[k * OUTC + j];
    hs2[(long long)i * OUTC + j] = dinv[i] * acc;
}

// ---------------- CSR buckets (dst-grouped src lists), then gather ----------------

__global__ void fill_bucket_kernel(const int* __restrict__ src, const int* __restrict__ dst, int E,
                                   int* __restrict__ cursor, int* __restrict__ bucket,
                                   int* __restrict__ ovf, int* __restrict__ ovf_cnt) {
    int e = blockIdx.x * blockDim.x + threadIdx.x;
    if (e < E) {
        int d = dst[e];
        int p = atomicAdd(&cursor[d], 1);
        if (p < BCAP) {
            bucket[d * BCAP + p] = src[e];
        } else {
            int o = atomicAdd(ovf_cnt, 1);
            if (o < OVF_CAP) { ovf[2 * o] = src[e]; ovf[2 * o + 1] = d; }
        }
    }
}

// one wave (64 lanes) per node; lane j owns feature j
__global__ void gather2_kernel(const int* __restrict__ cursor, const int* __restrict__ bucket,
                               const float* __restrict__ hs2, const float* __restrict__ dinv,
                               const float* __restrict__ b2, float* __restrict__ out, int N) {
    int wid = threadIdx.x >> 6;
    int j = threadIdx.x & 63;
    int d = blockIdx.x * 4 + wid;
    if (d >= N) return;
    int cnt = cursor[d];
    cnt = cnt < BCAP ? cnt : BCAP;
    int sv = (j < cnt) ? bucket[d * BCAP + j] : 0;  // coalesced 256B src-list load
    float acc = 0.0f;
    for (int k = 0; k < cnt; ++k) {
        int s = __shfl(sv, k, 64);
        acc += hs2[(long long)s * OUTC + j];        // coalesced 256B row from L2/L3
    }
    out[(long long)d * OUTC + j] = dinv[d] * (acc + hs2[(long long)d * OUTC + j]) + b2[j];
}

// adds contributions of (astronomically unlikely) bucket-overflow edges
__global__ void ovf_fallback_kernel(const int* __restrict__ ovf, const int* __restrict__ ovf_cnt,
                                    const float* __restrict__ hs2, const float* __restrict__ dinv,
                                    float* __restrict__ out) {
    int cnt = *ovf_cnt;
    cnt = cnt < OVF_CAP ? cnt : OVF_CAP;
    for (int t = threadIdx.x; t < cnt * OUTC; t += blockDim.x) {
        int o = t >> 6, j = t & 63;
        int s = ovf[2 * o], d = ovf[2 * o + 1];
        atomicAdd(&out[(long long)d * OUTC + j], dinv[d] * hs2[(long long)s * OUTC + j]);
    }
}

extern "C" void kernel_launch(void* const* d_in, const int* in_sizes, int n_in,
                              void* d_out, int out_size, void* d_ws, size_t ws_size,
                              hipStream_t stream) {
    const float* x  = (const float*)d_in[0];
    const int*   ei = (const int*)d_in[1];
    const float* W1 = (const float*)d_in[2];
    const float* b1 = (const float*)d_in[3];
    const float* W2 = (const float*)d_in[4];
    const float* b2 = (const float*)d_in[5];
    float* out = (float*)d_out;

    const int N = in_sizes[0] / INC;
    const int E = in_sizes[1] / 2;
    const int* src = ei;
    const int* dst = ei + E;

    // workspace layout (bytes):
    //   0        : degi/dinv   (N*4, in-place convert)
    //   262144   : cursor      (N*4)
    //   524288   : z           (N*3*4)
    //   1572864  : aggz        (N*3*4)
    //   2621440  : ovf_cnt(64B) + ovf list
    //   3670016  : a1 (N*128*4) -- later reused as bucket (N*64*4), a1 dead after mm2
    //   29270016 : hs2 (N*64*4)
    char* ws = (char*)d_ws;
    int*   degi   = (int*)ws;
    float* dinv   = (float*)ws;
    int*   cursor = (int*)(ws + 262144);
    float* z      = (float*)(ws + 524288);
    float* aggz   = (float*)(ws + 1572864);
    int*   ovf_cnt= (int*)(ws + 2621440);
    int*   ovf    = (int*)(ws + 2621440 + 64);
    float* a1     = (float*)(ws + 3670016);
    int*   bucket = (int*)(ws + 3670016);          // aliases a1 (a1 dead after mm2)
    float* hs2    = (float*)(ws + 3670016 + (size_t)N * HID * sizeof(float));

    const int B = 256;

    hipMemsetAsync(degi, 0, (size_t)N * sizeof(int), stream);
    hipMemsetAsync(cursor, 0, (size_t)N * sizeof(int), stream);
    hipMemsetAsync(aggz, 0, (size_t)N * INC * sizeof(float), stream);
    hipMemsetAsync(ovf_cnt, 0, 64, stream);

    count_deg_kernel<<<(E + B - 1) / B, B, 0, stream>>>(dst, E, degi);
    dinv_kernel<<<(N + B - 1) / B, B, 0, stream>>>(degi, N);

    // ---- layer 1 (3-dim aggregation) ----
    z_kernel<<<(N + B - 1) / B, B, 0, stream>>>(x, dinv, z, N);
    scatter_z_kernel<<<(E + B - 1) / B, B, 0, stream>>>(src, dst, E, z, aggz);
    a1_kernel<<<(N * HID + B - 1) / B, B, 0, stream>>>(z, aggz, dinv, W1, b1, a1, N);

    // ---- layer 2 ----
    mm2_kernel<<<N, 64, 0, stream>>>(a1, W2, dinv, hs2, N);
    fill_bucket_kernel<<<(E + B - 1) / B, B, 0, stream>>>(src, dst, E, cursor, bucket, ovf, ovf_cnt);
    gather2_kernel<<<(N + 3) / 4, B, 0, stream>>>(cursor, bucket, hs2, dinv, b2, out, N);
    ovf_fallback_kernel<<<1, B, 0, stream>>>(ovf, ovf_cnt, hs2, dinv, out);
}

// Round 3
// 241.482 us; speedup vs baseline: 2.9902x; 1.7240x over previous
//
#include <hip/hip_runtime.h>

#define HID 128
#define OUTC 64
#define INC 3
#define BCAP 64        // bucket capacity per node; in-deg ~ Poisson(16), P(>=64) ~ 1e-18
#define OVF_CAP 8192   // overflow edge list capacity (expected usage: 0)

// ---------------- CSR bucket build (dst-grouped src lists); cursor ends as in-degree --------

__global__ void fill_bucket_kernel(const int* __restrict__ src, const int* __restrict__ dst, int E,
                                   int* __restrict__ cursor, int* __restrict__ bucket,
                                   int* __restrict__ ovf, int* __restrict__ ovf_cnt) {
    int e = blockIdx.x * blockDim.x + threadIdx.x;
    if (e < E) {
        int d = dst[e];
        int p = atomicAdd(&cursor[d], 1);
        if (p < BCAP) {
            bucket[d * BCAP + p] = src[e];
        } else {
            int o = atomicAdd(ovf_cnt, 1);
            if (o < OVF_CAP) { ovf[2 * o] = src[e]; ovf[2 * o + 1] = d; }
        }
    }
}

__global__ void dinv_kernel(const int* __restrict__ cursor, float* __restrict__ dinv, int N) {
    int i = blockIdx.x * blockDim.x + threadIdx.x;
    if (i < N) dinv[i] = rsqrtf((float)(cursor[i] + 1));   // +1 = self loop
}

// ---------------- layer-1 aggregation in 3-dim space: agg[d] = sum dinv[s]*x[s] ----------------
// one wave per node; lane k owns bucket entry k; butterfly reduce 3 components

__global__ void gather1_kernel(const int* __restrict__ cursor, const int* __restrict__ bucket,
                               const float* __restrict__ x, const float* __restrict__ dinv,
                               float* __restrict__ agg, int N) {
    int wid = threadIdx.x >> 6;
    int j = threadIdx.x & 63;
    int d = blockIdx.x * 4 + wid;
    if (d >= N) return;
    int cnt = cursor[d];
    cnt = cnt < BCAP ? cnt : BCAP;
    float a0 = 0.f, a1 = 0.f, a2 = 0.f;
    if (j < cnt) {
        int s = bucket[d * BCAP + j];     // coalesced 256B
        float ds = dinv[s];
        a0 = ds * x[3 * s];
        a1 = ds * x[3 * s + 1];
        a2 = ds * x[3 * s + 2];
    }
#pragma unroll
    for (int o = 32; o > 0; o >>= 1) {
        a0 += __shfl_xor(a0, o, 64);
        a1 += __shfl_xor(a1, o, 64);
        a2 += __shfl_xor(a2, o, 64);
    }
    if (j == 0) {
        agg[3 * d]     = a0;
        agg[3 * d + 1] = a1;
        agg[3 * d + 2] = a2;
    }
}

// overflow edges (expected zero): add dinv[s]*x[s] into agg[d]
__global__ void ovf1_kernel(const int* __restrict__ ovf, const int* __restrict__ ovf_cnt,
                            const float* __restrict__ x, const float* __restrict__ dinv,
                            float* __restrict__ agg) {
    int cnt = *ovf_cnt;
    cnt = cnt < OVF_CAP ? cnt : OVF_CAP;
    for (int t = threadIdx.x; t < cnt * 3; t += blockDim.x) {
        int o = t / 3, c = t % 3;
        int s = ovf[2 * o], d = ovf[2 * o + 1];
        atomicAdd(&agg[3 * d + c], dinv[s] * x[3 * s + c]);
    }
}

// ---------------- fused hidden: u -> relu(u@W1+b1) -> hs2 = dinv * (h @ W2) ----------------
// one wave per node (4 nodes / 256-block); h staged in LDS; W1 (1.5KB)/W2 (32KB) from L1

__global__ void hidden_kernel(const float* __restrict__ agg, const float* __restrict__ x,
                              const float* __restrict__ dinv, const float* __restrict__ W1,
                              const float* __restrict__ b1, const float* __restrict__ W2,
                              float* __restrict__ hs2, int N) {
    __shared__ float h[4][HID];
    int wid = threadIdx.x >> 6;
    int j = threadIdx.x & 63;
    int d = blockIdx.x * 4 + wid;
    if (d < N) {
        float dd = dinv[d];
        float u0 = dd * (agg[3 * d]     + dd * x[3 * d]);
        float u1 = dd * (agg[3 * d + 1] + dd * x[3 * d + 1]);
        float u2 = dd * (agg[3 * d + 2] + dd * x[3 * d + 2]);
        float h0 = fmaxf(u0 * W1[j]      + u1 * W1[HID + j]      + u2 * W1[2 * HID + j]      + b1[j],      0.f);
        float h1 = fmaxf(u0 * W1[j + 64] + u1 * W1[HID + j + 64] + u2 * W1[2 * HID + j + 64] + b1[j + 64], 0.f);
        h[wid][j] = h0;
        h[wid][j + 64] = h1;
    }
    __syncthreads();
    if (d < N) {
        float acc = 0.f;
#pragma unroll
        for (int k = 0; k < HID; ++k) acc += h[wid][k] * W2[k * OUTC + j];
        hs2[(long long)d * OUTC + j] = dinv[d] * acc;
    }
}

// ---------------- layer-2 gather: out[d] = dinv[d]*(sum hs2[s] + hs2[d]) + b2 ----------------

__global__ void gather2_kernel(const int* __restrict__ cursor, const int* __restrict__ bucket,
                               const float* __restrict__ hs2, const float* __restrict__ dinv,
                               const float* __restrict__ b2, float* __restrict__ out, int N) {
    int wid = threadIdx.x >> 6;
    int j = threadIdx.x & 63;
    int d = blockIdx.x * 4 + wid;
    if (d >= N) return;
    int cnt = cursor[d];
    cnt = cnt < BCAP ? cnt : BCAP;
    int sv = (j < cnt) ? bucket[d * BCAP + j] : 0;  // coalesced 256B src-list load
    float acc = 0.0f;
    for (int k = 0; k < cnt; ++k) {
        int s = __shfl(sv, k, 64);
        acc += hs2[(long long)s * OUTC + j];        // coalesced 256B row from L2/L3
    }
    out[(long long)d * OUTC + j] = dinv[d] * (acc + hs2[(long long)d * OUTC + j]) + b2[j];
}

__global__ void ovf2_kernel(const int* __restrict__ ovf, const int* __restrict__ ovf_cnt,
                            const float* __restrict__ hs2, const float* __restrict__ dinv,
                            float* __restrict__ out) {
    int cnt = *ovf_cnt;
    cnt = cnt < OVF_CAP ? cnt : OVF_CAP;
    for (int t = threadIdx.x; t < cnt * OUTC; t += blockDim.x) {
        int o = t >> 6, j = t & 63;
        int s = ovf[2 * o], d = ovf[2 * o + 1];
        atomicAdd(&out[(long long)d * OUTC + j], dinv[d] * hs2[(long long)s * OUTC + j]);
    }
}

extern "C" void kernel_launch(void* const* d_in, const int* in_sizes, int n_in,
                              void* d_out, int out_size, void* d_ws, size_t ws_size,
                              hipStream_t stream) {
    const float* x  = (const float*)d_in[0];
    const int*   ei = (const int*)d_in[1];
    const float* W1 = (const float*)d_in[2];
    const float* b1 = (const float*)d_in[3];
    const float* W2 = (const float*)d_in[4];
    const float* b2 = (const float*)d_in[5];
    float* out = (float*)d_out;

    const int N = in_sizes[0] / INC;
    const int E = in_sizes[1] / 2;
    const int* src = ei;
    const int* dst = ei + E;

    // workspace layout (bytes):
    //   0        : cursor  (N*4)
    //   262144   : dinv    (N*4)
    //   524288   : agg     (N*3*4)
    //   1179648  : ovf_cnt (64B) + ovf (OVF_CAP*2*4)
    //   1310720  : bucket  (N*BCAP*4 = 12.8MB)
    //   14155776 : hs2     (N*OUTC*4 = 12.8MB)
    char* ws = (char*)d_ws;
    int*   cursor  = (int*)ws;
    float* dinv    = (float*)(ws + 262144);
    float* agg     = (float*)(ws + 524288);
    int*   ovf_cnt = (int*)(ws + 1179648);
    int*   ovf     = (int*)(ws + 1179648 + 64);
    int*   bucket  = (int*)(ws + 1310720);
    float* hs2     = (float*)(ws + 14155776);

    const int B = 256;

    hipMemsetAsync(cursor, 0, (size_t)N * sizeof(int), stream);
    hipMemsetAsync(ovf_cnt, 0, 64, stream);

    fill_bucket_kernel<<<(E + B - 1) / B, B, 0, stream>>>(src, dst, E, cursor, bucket, ovf, ovf_cnt);
    dinv_kernel<<<(N + B - 1) / B, B, 0, stream>>>(cursor, dinv, N);

    // ---- layer 1 (3-dim gather aggregation, no atomics) ----
    gather1_kernel<<<(N + 3) / 4, B, 0, stream>>>(cursor, bucket, x, dinv, agg, N);
    ovf1_kernel<<<1, B, 0, stream>>>(ovf, ovf_cnt, x, dinv, agg);

    // ---- fused hidden (a1 + mm2) ----
    hidden_kernel<<<(N + 3) / 4, B, 0, stream>>>(agg, x, dinv, W1, b1, W2, hs2, N);

    // ---- layer 2 gather ----
    gather2_kernel<<<(N + 3) / 4, B, 0, stream>>>(cursor, bucket, hs2, dinv, b2, out, N);
    ovf2_kernel<<<1, B, 0, stream>>>(ovf, ovf_cnt, hs2, dinv, out);
}

// Round 4
// 191.121 us; speedup vs baseline: 3.7781x; 1.2635x over previous
//
#include <hip/hip_runtime.h>

#define HID 128
#define OUTC 64
#define INC 3
#define BCAP 64        // bucket capacity per node; in-deg ~ Poisson(16), P(>=64) ~ 1e-18
#define OVF_CAP 8192   // overflow edge list capacity (expected usage: 0)
#define NT 64          // nodes per block in hidden GEMM

// ---------------- CSR bucket build (dst-grouped src lists); cursor ends as in-degree --------

template <typename IT>
__global__ void fill_bucket_kernel(const int* __restrict__ src, const int* __restrict__ dst, int E,
                                   int* __restrict__ cursor, IT* __restrict__ bucket,
                                   int* __restrict__ ovf, int* __restrict__ ovf_cnt) {
    int e = blockIdx.x * blockDim.x + threadIdx.x;
    if (e < E) {
        int d = dst[e];
        int p = atomicAdd(&cursor[d], 1);
        if (p < BCAP) {
            bucket[(size_t)d * BCAP + p] = (IT)src[e];
        } else {
            int o = atomicAdd(ovf_cnt, 1);
            if (o < OVF_CAP) { ovf[2 * o] = src[e]; ovf[2 * o + 1] = d; }
        }
    }
}

// ---------------- z4 = (dinv*x0, dinv*x1, dinv*x2, dinv) ----------------

__global__ void z4_kernel(const float* __restrict__ x, const int* __restrict__ cursor,
                          float4* __restrict__ z4, int N) {
    int i = blockIdx.x * blockDim.x + threadIdx.x;
    if (i < N) {
        float dd = rsqrtf((float)(cursor[i] + 1));   // +1 = self loop
        z4[i] = make_float4(dd * x[3 * i], dd * x[3 * i + 1], dd * x[3 * i + 2], dd);
    }
}

// ---------------- layer-1 aggregation in 3-dim space: agg4[d] = sum z4[s].xyz ----------------

template <typename IT>
__global__ void gather1_kernel(const int* __restrict__ cursor, const IT* __restrict__ bucket,
                               const float4* __restrict__ z4, float4* __restrict__ agg4, int N) {
    int wid = threadIdx.x >> 6;
    int j = threadIdx.x & 63;
    int d = blockIdx.x * 4 + wid;
    if (d >= N) return;
    int cnt = cursor[d];
    cnt = cnt < BCAP ? cnt : BCAP;
    float a0 = 0.f, a1 = 0.f, a2 = 0.f;
    if (j < cnt) {
        int s = (int)bucket[(size_t)d * BCAP + j];   // coalesced list load
        float4 zv = z4[s];                            // one aligned 16B load
        a0 = zv.x; a1 = zv.y; a2 = zv.z;
    }
#pragma unroll
    for (int o = 32; o > 0; o >>= 1) {
        a0 += __shfl_xor(a0, o, 64);
        a1 += __shfl_xor(a1, o, 64);
        a2 += __shfl_xor(a2, o, 64);
    }
    if (j == 0) agg4[d] = make_float4(a0, a1, a2, 0.f);
}

__global__ void ovf1_kernel(const int* __restrict__ ovf, const int* __restrict__ ovf_cnt,
                            const float4* __restrict__ z4, float4* __restrict__ agg4) {
    int cnt = *ovf_cnt;
    cnt = cnt < OVF_CAP ? cnt : OVF_CAP;
    for (int t = threadIdx.x; t < cnt; t += blockDim.x) {
        int s = ovf[2 * t], d = ovf[2 * t + 1];
        float4 zv = z4[s];
        float* a = (float*)&agg4[d];
        atomicAdd(a + 0, zv.x);
        atomicAdd(a + 1, zv.y);
        atomicAdd(a + 2, zv.z);
    }
}

// ---------------- fused hidden GEMM: u -> relu(u@W1+b1) -> hs2 = dinv*(h@W2) ----------------
// 64 nodes x 64 outputs per 256-thread block; 4x4 register tile per thread;
// h (k-major) and W2 both staged in LDS (64KB total -> 2 blocks/CU)

__global__ __launch_bounds__(256) void hidden_kernel(const float4* __restrict__ agg4,
                                                     const float4* __restrict__ z4,
                                                     const float* __restrict__ W1,
                                                     const float* __restrict__ b1,
                                                     const float* __restrict__ W2,
                                                     float* __restrict__ hs2, int N) {
    __shared__ float h_s[HID][NT];       // 32 KB, k-major
    __shared__ float w_s[HID * OUTC];    // 32 KB
    int t = threadIdx.x;
    int base = blockIdx.x * NT;

    for (int i = t; i < HID * OUTC; i += 256) w_s[i] = W2[i];

    // stage 1: each thread owns node n = t&63, computes 32 hidden values (k = t>>6 + 4i)
    {
        int n = t & 63;
        int d = base + n;
        float u0 = 0.f, u1 = 0.f, u2 = 0.f;
        if (d < N) {
            float4 zv = z4[d];
            float4 av = agg4[d];
            float dd = zv.w;
            u0 = dd * (av.x + zv.x);
            u1 = dd * (av.y + zv.y);
            u2 = dd * (av.z + zv.z);
        }
        int k0 = t >> 6;
#pragma unroll
        for (int i = 0; i < HID / 4; ++i) {
            int k = k0 + 4 * i;                       // wave-uniform -> scalar W1/b1 loads
            float v = u0 * W1[k] + u1 * W1[HID + k] + u2 * W1[2 * HID + k] + b1[k];
            h_s[k][n] = fmaxf(v, 0.f);
        }
    }
    __syncthreads();

    // stage 2: 16x16 thread grid, 4x4 register tile
    int tx = t & 15, ty = t >> 4;
    float acc[4][4] = {};
#pragma unroll 8
    for (int k = 0; k < HID; ++k) {
        float4 hv = *(const float4*)&h_s[k][ty * 4];
        float4 wv = *(const float4*)&w_s[k * OUTC + tx * 4];
        float hr[4] = {hv.x, hv.y, hv.z, hv.w};
        float wr[4] = {wv.x, wv.y, wv.z, wv.w};
#pragma unroll
        for (int r = 0; r < 4; ++r)
#pragma unroll
            for (int c = 0; c < 4; ++c) acc[r][c] = fmaf(hr[r], wr[c], acc[r][c]);
    }

#pragma unroll
    for (int r = 0; r < 4; ++r) {
        int n = ty * 4 + r;
        int d = base + n;
        if (d < N) {
            float dd = z4[d].w;
            float4 o = make_float4(dd * acc[r][0], dd * acc[r][1], dd * acc[r][2], dd * acc[r][3]);
            *(float4*)&hs2[(size_t)d * OUTC + tx * 4] = o;
        }
    }
}

// ---------------- layer-2 gather: out[d] = dinv[d]*(sum hs2[s] + hs2[d]) + b2 ----------------

template <typename IT>
__global__ void gather2_kernel(const int* __restrict__ cursor, const IT* __restrict__ bucket,
                               const float* __restrict__ hs2, const float4* __restrict__ z4,
                               const float* __restrict__ b2, float* __restrict__ out, int N) {
    int wid = threadIdx.x >> 6;
    int j = threadIdx.x & 63;
    int d = blockIdx.x * 4 + wid;
    if (d >= N) return;
    int cnt = cursor[d];
    cnt = cnt < BCAP ? cnt : BCAP;
    int sv = (j < cnt) ? (int)bucket[(size_t)d * BCAP + j] : 0;
    float acc = 0.0f;
    int k = 0;
    for (; k + 4 <= cnt; k += 4) {                    // 4 independent loads in flight
        int s0 = __shfl(sv, k, 64), s1 = __shfl(sv, k + 1, 64);
        int s2 = __shfl(sv, k + 2, 64), s3 = __shfl(sv, k + 3, 64);
        float v0 = hs2[(size_t)s0 * OUTC + j], v1 = hs2[(size_t)s1 * OUTC + j];
        float v2 = hs2[(size_t)s2 * OUTC + j], v3 = hs2[(size_t)s3 * OUTC + j];
        acc += (v0 + v1) + (v2 + v3);
    }
    for (; k < cnt; ++k) {
        int s = __shfl(sv, k, 64);
        acc += hs2[(size_t)s * OUTC + j];
    }
    float dd = z4[d].w;
    out[(size_t)d * OUTC + j] = dd * (acc + hs2[(size_t)d * OUTC + j]) + b2[j];
}

__global__ void ovf2_kernel(const int* __restrict__ ovf, const int* __restrict__ ovf_cnt,
                            const float* __restrict__ hs2, const float4* __restrict__ z4,
                            float* __restrict__ out) {
    int cnt = *ovf_cnt;
    cnt = cnt < OVF_CAP ? cnt : OVF_CAP;
    for (int t = threadIdx.x; t < cnt * OUTC; t += blockDim.x) {
        int o = t >> 6, j = t & 63;
        int s = ovf[2 * o], d = ovf[2 * o + 1];
        atomicAdd(&out[(size_t)d * OUTC + j], z4[d].w * hs2[(size_t)s * OUTC + j]);
    }
}

static inline size_t align256(size_t v) { return (v + 255) & ~(size_t)255; }

extern "C" void kernel_launch(void* const* d_in, const int* in_sizes, int n_in,
                              void* d_out, int out_size, void* d_ws, size_t ws_size,
                              hipStream_t stream) {
    const float* x  = (const float*)d_in[0];
    const int*   ei = (const int*)d_in[1];
    const float* W1 = (const float*)d_in[2];
    const float* b1 = (const float*)d_in[3];
    const float* W2 = (const float*)d_in[4];
    const float* b2 = (const float*)d_in[5];
    float* out = (float*)d_out;

    const int N = in_sizes[0] / INC;
    const int E = in_sizes[1] / 2;
    const int* src = ei;
    const int* dst = ei + E;
    const bool u16 = (N <= 65535);

    char* ws = (char*)d_ws;
    size_t off = 0;
    int*    cursor  = (int*)(ws + off);    off += align256((size_t)N * 4);
    float4* z4      = (float4*)(ws + off); off += align256((size_t)N * 16);
    float4* agg4    = (float4*)(ws + off); off += align256((size_t)N * 16);
    int*    ovf_cnt = (int*)(ws + off);    off += 256;
    int*    ovf     = (int*)(ws + off);    off += (size_t)OVF_CAP * 8;
    void*   bucket  = (void*)(ws + off);   off += align256((size_t)N * BCAP * (u16 ? 2 : 4));
    float*  hs2     = (float*)(ws + off);  off += (size_t)N * OUTC * 4;

    const int B = 256;

    hipMemsetAsync(cursor, 0, (size_t)N * sizeof(int), stream);
    hipMemsetAsync(ovf_cnt, 0, 64, stream);

    if (u16)
        fill_bucket_kernel<unsigned short><<<(E + B - 1) / B, B, 0, stream>>>(
            src, dst, E, cursor, (unsigned short*)bucket, ovf, ovf_cnt);
    else
        fill_bucket_kernel<int><<<(E + B - 1) / B, B, 0, stream>>>(
            src, dst, E, cursor, (int*)bucket, ovf, ovf_cnt);

    z4_kernel<<<(N + B - 1) / B, B, 0, stream>>>(x, cursor, z4, N);

    // ---- layer 1 (3-dim gather aggregation, no atomics) ----
    if (u16)
        gather1_kernel<unsigned short><<<(N + 3) / 4, B, 0, stream>>>(
            cursor, (const unsigned short*)bucket, z4, agg4, N);
    else
        gather1_kernel<int><<<(N + 3) / 4, B, 0, stream>>>(
            cursor, (const int*)bucket, z4, agg4, N);
    ovf1_kernel<<<1, B, 0, stream>>>(ovf, ovf_cnt, z4, agg4);

    // ---- fused hidden (relu(u@W1+b1) @ W2, register-tiled GEMM) ----
    hidden_kernel<<<(N + NT - 1) / NT, 256, 0, stream>>>(agg4, z4, W1, b1, W2, hs2, N);

    // ---- layer 2 gather ----
    if (u16)
        gather2_kernel<unsigned short><<<(N + 3) / 4, B, 0, stream>>>(
            cursor, (const unsigned short*)bucket, hs2, z4, b2, out, N);
    else
        gather2_kernel<int><<<(N + 3) / 4, B, 0, stream>>>(
            cursor, (const int*)bucket, hs2, z4, b2, out, N);
    ovf2_kernel<<<1, B, 0, stream>>>(ovf, ovf_cnt, hs2, z4, out);
}

// Round 5
// 187.001 us; speedup vs baseline: 3.8613x; 1.0220x over previous
//
#include <hip/hip_runtime.h>
#include <hip/hip_bf16.h>

#define HID 128
#define OUTC 64
#define INC 3
#define BCAP 64        // bucket capacity per node; in-deg ~ Poisson(16), P(>=64) ~ 1e-18
#define OVF_CAP 8192   // overflow edge list capacity (expected usage: 0)
#define NT 64          // nodes per block in hidden GEMM
#define EPT 4          // edges per thread in fill_bucket (ILP for atomic latency)

static __device__ __forceinline__ unsigned short f2bf(float f) {
    __hip_bfloat16 b = __float2bfloat16(f);
    return *reinterpret_cast<unsigned short*>(&b);
}
static __device__ __forceinline__ float bf2f(unsigned short u) {
    __hip_bfloat16 b = *reinterpret_cast<__hip_bfloat16*>(&u);
    return __bfloat162float(b);
}

// ---------------- CSR bucket build (dst-grouped src lists); cursor ends as in-degree --------
// EPT independent atomic->write chains per thread to hide device-atomic latency

template <typename IT>
__global__ void fill_bucket_kernel(const int* __restrict__ src, const int* __restrict__ dst, int E,
                                   int T, int* __restrict__ cursor, IT* __restrict__ bucket,
                                   int* __restrict__ ovf, int* __restrict__ ovf_cnt) {
    int tid = blockIdx.x * blockDim.x + threadIdx.x;
    int d[EPT], s[EPT], p[EPT];
    bool v[EPT];
#pragma unroll
    for (int k = 0; k < EPT; ++k) {
        int e = tid + k * T;                 // coalesced across threads
        v[k] = (e < E);
        d[k] = v[k] ? dst[e] : 0;
        s[k] = v[k] ? src[e] : 0;
    }
#pragma unroll
    for (int k = 0; k < EPT; ++k)
        if (v[k]) p[k] = atomicAdd(&cursor[d[k]], 1);   // EPT independent atomics in flight
#pragma unroll
    for (int k = 0; k < EPT; ++k) {
        if (v[k]) {
            if (p[k] < BCAP) {
                __builtin_nontemporal_store((IT)s[k], &bucket[(size_t)d[k] * BCAP + p[k]]);
            } else {
                int o = atomicAdd(ovf_cnt, 1);
                if (o < OVF_CAP) { ovf[2 * o] = s[k]; ovf[2 * o + 1] = d[k]; }
            }
        }
    }
}

// ---------------- z4 = (dinv*x0, dinv*x1, dinv*x2, dinv) ----------------

__global__ void z4_kernel(const float* __restrict__ x, const int* __restrict__ cursor,
                          float4* __restrict__ z4, int N) {
    int i = blockIdx.x * blockDim.x + threadIdx.x;
    if (i < N) {
        float dd = rsqrtf((float)(cursor[i] + 1));   // +1 = self loop
        z4[i] = make_float4(dd * x[3 * i], dd * x[3 * i + 1], dd * x[3 * i + 2], dd);
    }
}

// ---------------- layer-1 aggregation in 3-dim space: agg4[d] = sum z4[s].xyz ----------------

template <typename IT>
__global__ void gather1_kernel(const int* __restrict__ cursor, const IT* __restrict__ bucket,
                               const float4* __restrict__ z4, float4* __restrict__ agg4, int N) {
    int wid = threadIdx.x >> 6;
    int j = threadIdx.x & 63;
    int d = blockIdx.x * 4 + wid;
    if (d >= N) return;
    int cnt = cursor[d];
    cnt = cnt < BCAP ? cnt : BCAP;
    float a0 = 0.f, a1 = 0.f, a2 = 0.f;
    if (j < cnt) {
        int s = (int)bucket[(size_t)d * BCAP + j];   // coalesced list load
        float4 zv = z4[s];                            // one aligned 16B load
        a0 = zv.x; a1 = zv.y; a2 = zv.z;
    }
#pragma unroll
    for (int o = 32; o > 0; o >>= 1) {
        a0 += __shfl_xor(a0, o, 64);
        a1 += __shfl_xor(a1, o, 64);
        a2 += __shfl_xor(a2, o, 64);
    }
    if (j == 0) agg4[d] = make_float4(a0, a1, a2, 0.f);
}

__global__ void ovf1_kernel(const int* __restrict__ ovf, const int* __restrict__ ovf_cnt,
                            const float4* __restrict__ z4, float4* __restrict__ agg4) {
    int cnt = *ovf_cnt;
    cnt = cnt < OVF_CAP ? cnt : OVF_CAP;
    for (int t = threadIdx.x; t < cnt; t += blockDim.x) {
        int s = ovf[2 * t], d = ovf[2 * t + 1];
        float4 zv = z4[s];
        float* a = (float*)&agg4[d];
        atomicAdd(a + 0, zv.x);
        atomicAdd(a + 1, zv.y);
        atomicAdd(a + 2, zv.z);
    }
}

// ---------------- fused hidden GEMM: u -> relu(u@W1+b1) -> hs2 = dinv*(h@W2), bf16 out ----------

__global__ __launch_bounds__(256) void hidden_kernel(const float4* __restrict__ agg4,
                                                     const float4* __restrict__ z4,
                                                     const float* __restrict__ W1,
                                                     const float* __restrict__ b1,
                                                     const float* __restrict__ W2,
                                                     unsigned short* __restrict__ hs2b, int N) {
    __shared__ float h_s[HID][NT];       // 32 KB, k-major
    __shared__ float w_s[HID * OUTC];    // 32 KB
    int t = threadIdx.x;
    int base = blockIdx.x * NT;

    for (int i = t; i < HID * OUTC; i += 256) w_s[i] = W2[i];

    // stage 1: each thread owns node n = t&63, computes 32 hidden values (k = t>>6 + 4i)
    {
        int n = t & 63;
        int d = base + n;
        float u0 = 0.f, u1 = 0.f, u2 = 0.f;
        if (d < N) {
            float4 zv = z4[d];
            float4 av = agg4[d];
            float dd = zv.w;
            u0 = dd * (av.x + zv.x);
            u1 = dd * (av.y + zv.y);
            u2 = dd * (av.z + zv.z);
        }
        int k0 = t >> 6;
#pragma unroll
        for (int i = 0; i < HID / 4; ++i) {
            int k = k0 + 4 * i;                       // wave-uniform -> scalar W1/b1 loads
            float v = u0 * W1[k] + u1 * W1[HID + k] + u2 * W1[2 * HID + k] + b1[k];
            h_s[k][n] = fmaxf(v, 0.f);
        }
    }
    __syncthreads();

    // stage 2: 16x16 thread grid, 4x4 register tile
    int tx = t & 15, ty = t >> 4;
    float acc[4][4] = {};
#pragma unroll 8
    for (int k = 0; k < HID; ++k) {
        float4 hv = *(const float4*)&h_s[k][ty * 4];
        float4 wv = *(const float4*)&w_s[k * OUTC + tx * 4];
        float hr[4] = {hv.x, hv.y, hv.z, hv.w};
        float wr[4] = {wv.x, wv.y, wv.z, wv.w};
#pragma unroll
        for (int r = 0; r < 4; ++r)
#pragma unroll
            for (int c = 0; c < 4; ++c) acc[r][c] = fmaf(hr[r], wr[c], acc[r][c]);
    }

#pragma unroll
    for (int r = 0; r < 4; ++r) {
        int n = ty * 4 + r;
        int d = base + n;
        if (d < N) {
            float dd = z4[d].w;
            ushort4 o;
            o.x = f2bf(dd * acc[r][0]);
            o.y = f2bf(dd * acc[r][1]);
            o.z = f2bf(dd * acc[r][2]);
            o.w = f2bf(dd * acc[r][3]);
            *(ushort4*)&hs2b[(size_t)d * OUTC + tx * 4] = o;   // 8B aligned store
        }
    }
}

// ---------------- layer-2 gather: out[d] = dinv[d]*(sum hs2[s] + hs2[d]) + b2 ----------------

template <typename IT>
__global__ void gather2_kernel(const int* __restrict__ cursor, const IT* __restrict__ bucket,
                               const unsigned short* __restrict__ hs2b, const float4* __restrict__ z4,
                               const float* __restrict__ b2, float* __restrict__ out, int N) {
    int wid = threadIdx.x >> 6;
    int j = threadIdx.x & 63;
    int d = blockIdx.x * 4 + wid;
    if (d >= N) return;
    int cnt = cursor[d];
    cnt = cnt < BCAP ? cnt : BCAP;
    int sv = (j < cnt) ? (int)bucket[(size_t)d * BCAP + j] : 0;
    float acc = 0.0f;
    int k = 0;
    for (; k + 4 <= cnt; k += 4) {                    // 4 independent row loads in flight
        int s0 = __shfl(sv, k, 64), s1 = __shfl(sv, k + 1, 64);
        int s2 = __shfl(sv, k + 2, 64), s3 = __shfl(sv, k + 3, 64);
        float v0 = bf2f(hs2b[(size_t)s0 * OUTC + j]);
        float v1 = bf2f(hs2b[(size_t)s1 * OUTC + j]);
        float v2 = bf2f(hs2b[(size_t)s2 * OUTC + j]);
        float v3 = bf2f(hs2b[(size_t)s3 * OUTC + j]);
        acc += (v0 + v1) + (v2 + v3);
    }
    for (; k < cnt; ++k) {
        int s = __shfl(sv, k, 64);
        acc += bf2f(hs2b[(size_t)s * OUTC + j]);
    }
    float dd = z4[d].w;
    out[(size_t)d * OUTC + j] = dd * (acc + bf2f(hs2b[(size_t)d * OUTC + j])) + b2[j];
}

__global__ void ovf2_kernel(const int* __restrict__ ovf, const int* __restrict__ ovf_cnt,
                            const unsigned short* __restrict__ hs2b, const float4* __restrict__ z4,
                            float* __restrict__ out) {
    int cnt = *ovf_cnt;
    cnt = cnt < OVF_CAP ? cnt : OVF_CAP;
    for (int t = threadIdx.x; t < cnt * OUTC; t += blockDim.x) {
        int o = t >> 6, j = t & 63;
        int s = ovf[2 * o], d = ovf[2 * o + 1];
        atomicAdd(&out[(size_t)d * OUTC + j], z4[d].w * bf2f(hs2b[(size_t)s * OUTC + j]));
    }
}

static inline size_t align256(size_t v) { return (v + 255) & ~(size_t)255; }

extern "C" void kernel_launch(void* const* d_in, const int* in_sizes, int n_in,
                              void* d_out, int out_size, void* d_ws, size_t ws_size,
                              hipStream_t stream) {
    const float* x  = (const float*)d_in[0];
    const int*   ei = (const int*)d_in[1];
    const float* W1 = (const float*)d_in[2];
    const float* b1 = (const float*)d_in[3];
    const float* W2 = (const float*)d_in[4];
    const float* b2 = (const float*)d_in[5];
    float* out = (float*)d_out;

    const int N = in_sizes[0] / INC;
    const int E = in_sizes[1] / 2;
    const int* src = ei;
    const int* dst = ei + E;
    const bool u16 = (N <= 65535);

    char* ws = (char*)d_ws;
    size_t off = 0;
    int*    cursor  = (int*)(ws + off);    off += align256((size_t)N * 4);
    float4* z4      = (float4*)(ws + off); off += align256((size_t)N * 16);
    float4* agg4    = (float4*)(ws + off); off += align256((size_t)N * 16);
    int*    ovf_cnt = (int*)(ws + off);    off += 256;
    int*    ovf     = (int*)(ws + off);    off += (size_t)OVF_CAP * 8;
    void*   bucket  = (void*)(ws + off);   off += align256((size_t)N * BCAP * (u16 ? 2 : 4));
    unsigned short* hs2b = (unsigned short*)(ws + off); off += (size_t)N * OUTC * 2;

    const int B = 256;

    hipMemsetAsync(cursor, 0, (size_t)N * sizeof(int), stream);
    hipMemsetAsync(ovf_cnt, 0, 64, stream);

    {
        int grid = (E + B * EPT - 1) / (B * EPT);
        int T = grid * B;
        if (u16)
            fill_bucket_kernel<unsigned short><<<grid, B, 0, stream>>>(
                src, dst, E, T, cursor, (unsigned short*)bucket, ovf, ovf_cnt);
        else
            fill_bucket_kernel<int><<<grid, B, 0, stream>>>(
                src, dst, E, T, cursor, (int*)bucket, ovf, ovf_cnt);
    }

    z4_kernel<<<(N + B - 1) / B, B, 0, stream>>>(x, cursor, z4, N);

    // ---- layer 1 (3-dim gather aggregation, no atomics) ----
    if (u16)
        gather1_kernel<unsigned short><<<(N + 3) / 4, B, 0, stream>>>(
            cursor, (const unsigned short*)bucket, z4, agg4, N);
    else
        gather1_kernel<int><<<(N + 3) / 4, B, 0, stream>>>(
            cursor, (const int*)bucket, z4, agg4, N);
    ovf1_kernel<<<1, B, 0, stream>>>(ovf, ovf_cnt, z4, agg4);

    // ---- fused hidden (relu(u@W1+b1) @ W2, register-tiled GEMM, bf16 out) ----
    hidden_kernel<<<(N + NT - 1) / NT, 256, 0, stream>>>(agg4, z4, W1, b1, W2, hs2b, N);

    // ---- layer 2 gather ----
    if (u16)
        gather2_kernel<unsigned short><<<(N + 3) / 4, B, 0, stream>>>(
            cursor, (const unsigned short*)bucket, hs2b, z4, b2, out, N);
    else
        gather2_kernel<int><<<(N + 3) / 4, B, 0, stream>>>(
            cursor, (const int*)bucket, hs2b, z4, b2, out, N);
    ovf2_kernel<<<1, B, 0, stream>>>(ovf, ovf_cnt, hs2b, z4, out);
}